// Round 9
// baseline (12209.027 us; speedup 1.0000x reference)
//
#include <hip/hip_runtime.h>
#include <stdint.h>

#define N      12288
#define CH     512
#define TI     128               // i-rows per block
#define TJ     256               // j-cols per tile (row = 1 KB: one DMA inst)
#define KC     16                // k-chunk (double-buffered)
#define NCHUNK (CH / KC)         // 32
#define NIT    (N / TI)          // 96 i-tiles
#define NJT    (N / TJ)          // 48 j-tiles
#define NS     8                 // j-slices
#define JT_PER_S (NJT / NS)      // 6 j-tiles per block
#define NCP    (NIT * 4)         // 384 col-partial slots (per i-tile x wave)

struct Top2 { float v0, v1; int i0, i1; };

// ---- module-scope device scratch (static, graph-capture safe) ----
__device__ float g_An[(size_t)CH * N];   // 25 MB normalized A
__device__ float g_Bn[(size_t)CH * N];   // 25 MB normalized B
__device__ Top2  g_rpart[NS][N];         // row top-2 partials (1.6 MB)
__device__ Top2  g_cpart[NCP][N];        // col top-2 partials (75 MB)
__device__ int   g_nn12[N];
__device__ float g_r12[N];
__device__ float g_sim0[N];
__device__ int   g_nn21[N];
__device__ float g_r21[N];

__device__ __forceinline__ void t2_ins(float v, int idx,
                                       float& v0, int& i0, float& v1, int& i1) {
  bool beats0 = (v > v0) || (v == v0 && idx < i0);
  bool beats1 = (v > v1) || (v == v1 && idx < i1);
  if (beats0) { v1 = v0; i1 = i0; v0 = v; i0 = idx; }
  else if (beats1) { v1 = v; i1 = idx; }
}

__device__ __forceinline__ float bf16_quant(float f) {
  unsigned int u = __float_as_uint(f);
  unsigned int r = 0x7fffu + ((u >> 16) & 1u);
  unsigned int q = ((u + r) >> 16) << 16;
  return __uint_as_float(q);
}

// async global->LDS DMA, 16 B/lane; LDS dest = wave-uniform base + lane*16
__device__ __forceinline__ void glds16(const float* g, float* l) {
  __builtin_amdgcn_global_load_lds((const __attribute__((address_space(1))) void*)g,
                                   (__attribute__((address_space(3))) void*)l, 16, 0, 0);
}

// -------------------- kernel 1: normalize descriptors (np: d / sqrt(sum d^2)) ----
__global__ void normalize_kernel(const float* __restrict__ A,
                                 const float* __restrict__ B) {
  int i = blockIdx.x * 256 + threadIdx.x;
  if (i >= N) return;
  float sa = 0.f, sb = 0.f;
  for (int c = 0; c < CH; ++c) {
    float a = A[(size_t)c * N + i];
    float b = B[(size_t)c * N + i];
    sa += a * a;
    sb += b * b;
  }
  float na = sqrtf(sa), nb = sqrtf(sb);
  for (int c = 0; c < CH; ++c) {
    g_An[(size_t)c * N + i] = A[(size_t)c * N + i] / na;
    g_Bn[(size_t)c * N + i] = B[(size_t)c * N + i] / nb;
  }
}

// -------------------- kernel 2: sim GEMM (DMA-staged, dbuf) + row/col top-2 ----
// grid (96, 8): i-tile x j-slice (6 j-tiles of 256 cols each).
// Thread tile 8x16 (rows: 2 quadrants of 4; cols: 4 quadrants of 4).
__global__ __launch_bounds__(256, 3)
void sim_kernel() {
  __shared__ float Xs[2][KC * TI];   // 16 KB
  __shared__ float Ys[2][KC * TJ];   // 32 KB
  __shared__ Top2  rowTop[TI];       // 2 KB

  const int itile = blockIdx.x;
  const int slice = blockIdx.y;
  const int i0 = itile * TI;
  const int tid  = threadIdx.x;
  const int tx = tid & 15;
  const int ty = tid >> 4;       // 0..15
  const int w  = tid >> 6;       // wave 0..3
  const int lane = tid & 63;

  if (tid < TI) {
    rowTop[tid].v0 = -1e30f; rowTop[tid].v1 = -1e30f;
    rowTop[tid].i0 = 0x7fffffff; rowTop[tid].i1 = 0x7fffffff;
  }

  // per-lane DMA source pointers (lane-constant parts)
  // Xs inst m (0..7): covers k = 2m + (lane>>5), col = (lane&31)*4
  const float* gx = g_An + (size_t)(lane >> 5) * N + i0 + (lane & 31) * 4;
  // Ys inst m (0..15): covers k = m, col = lane*4
  const float* gy = g_Bn + lane * 4;

  float acc[8][16];

#define ISSUE_CHUNK(GCH)                                                        \
  {                                                                             \
    const int jt_ = (GCH) >> 5, c_ = (GCH) & 31, buf_ = (GCH) & 1;              \
    const int kc_ = c_ * KC;                                                    \
    const int j0_ = (slice * JT_PER_S + jt_) * TJ;                              \
    _Pragma("unroll")                                                           \
    for (int t = 0; t < 2; ++t) {                                               \
      const int m = w * 2 + t;                                                  \
      glds16(gx + (size_t)(kc_ + 2 * m) * N, &Xs[buf_][m * 256]);               \
    }                                                                           \
    _Pragma("unroll")                                                           \
    for (int t = 0; t < 4; ++t) {                                               \
      const int m = w * 4 + t;                                                  \
      glds16(gy + (size_t)(kc_ + m) * N + j0_, &Ys[buf_][m * 256]);             \
    }                                                                           \
  }

  ISSUE_CHUNK(0);
  int g = 0;

  for (int jt = 0; jt < JT_PER_S; ++jt) {
    const int j0 = (slice * JT_PER_S + jt) * TJ;
#pragma unroll
    for (int u = 0; u < 8; ++u)
#pragma unroll
      for (int v = 0; v < 16; ++v) acc[u][v] = 0.f;

    for (int c = 0; c < NCHUNK; ++c, ++g) {
      __syncthreads();                      // drains own DMA (vmcnt) + barrier
      const int gn = g + 1;
      if (gn < JT_PER_S * NCHUNK) ISSUE_CHUNK(gn);   // prefetch into other buf

      const float* xb = Xs[g & 1];
      const float* yb = Ys[g & 1];
#pragma unroll
      for (int k = 0; k < KC; ++k) {
        float a[8] __attribute__((aligned(16)));
        *reinterpret_cast<float4*>(&a[0]) = *reinterpret_cast<const float4*>(&xb[k * TI + ty * 4]);
        *reinterpret_cast<float4*>(&a[4]) = *reinterpret_cast<const float4*>(&xb[k * TI + 64 + ty * 4]);
#pragma unroll
        for (int q = 0; q < 4; ++q) {
          float b[4] __attribute__((aligned(16)));
          *reinterpret_cast<float4*>(&b[0]) = *reinterpret_cast<const float4*>(&yb[k * TJ + q * 64 + tx * 4]);
#pragma unroll
          for (int u = 0; u < 8; ++u)
#pragma unroll
            for (int cc = 0; cc < 4; ++cc)
              acc[u][q * 4 + cc] += a[u] * b[cc];
        }
      }
    }

    // ---- epilogue: acc IS cosine sim (inputs pre-normalized) ----
    // row top-2: reduce across tx (masks 1..8), accumulate in rowTop
#pragma unroll
    for (int u = 0; u < 8; ++u) {
      float v0 = -1e30f, v1 = -1e30f; int id0 = 0x7fffffff, id1 = 0x7fffffff;
#pragma unroll
      for (int v = 0; v < 16; ++v) {
        int col = (v >> 2) * 64 + tx * 4 + (v & 3);
        t2_ins(acc[u][v], j0 + col, v0, id0, v1, id1);
      }
#pragma unroll
      for (int m = 1; m < 16; m <<= 1) {
        float ov0 = __shfl_xor(v0, m), ov1 = __shfl_xor(v1, m);
        int   oi0 = __shfl_xor(id0, m), oi1 = __shfl_xor(id1, m);
        t2_ins(ov0, oi0, v0, id0, v1, id1);
        t2_ins(ov1, oi1, v0, id0, v1, id1);
      }
      if (tx == 0) {   // unique owner per row
        int row = (u >> 2) * 64 + ty * 4 + (u & 3);
        Top2 t = rowTop[row];
        t2_ins(v0, id0, t.v0, t.i0, t.v1, t.i1);
        t2_ins(v1, id1, t.v0, t.i0, t.v1, t.i1);
        rowTop[row] = t;
      }
    }

    // col top-2: reduce 8 local rows, then ty within wave (masks 16,32);
    // per-wave partial straight to global (no LDS, no atomics)
#pragma unroll
    for (int v = 0; v < 16; ++v) {
      float v0 = -1e30f, v1 = -1e30f; int id0 = 0x7fffffff, id1 = 0x7fffffff;
#pragma unroll
      for (int u = 0; u < 8; ++u) {
        int row = (u >> 2) * 64 + ty * 4 + (u & 3);
        t2_ins(acc[u][v], i0 + row, v0, id0, v1, id1);
      }
#pragma unroll
      for (int m = 16; m < 64; m <<= 1) {
        float ov0 = __shfl_xor(v0, m), ov1 = __shfl_xor(v1, m);
        int   oi0 = __shfl_xor(id0, m), oi1 = __shfl_xor(id1, m);
        t2_ins(ov0, oi0, v0, id0, v1, id1);
        t2_ins(ov1, oi1, v0, id0, v1, id1);
      }
      if ((lane >> 4) == 0) {
        int col = (v >> 2) * 64 + tx * 4 + (v & 3);
        Top2 t; t.v0 = v0; t.v1 = v1; t.i0 = id0; t.i1 = id1;
        g_cpart[itile * 4 + w][j0 + col] = t;
      }
    }
  }

  __syncthreads();
  if (tid < TI) g_rpart[slice][i0 + tid] = rowTop[tid];
#undef ISSUE_CHUNK
}

// -------------------- kernel 3: merge partials --------------------
__global__ void merge_kernel() {
  int i = blockIdx.x * 256 + threadIdx.x;
  if (i >= N) return;
  {
    float v0 = -1e30f, v1 = -1e30f; int id0 = 0x7fffffff, id1 = 0x7fffffff;
#pragma unroll
    for (int s = 0; s < NS; ++s) {
      Top2 p = g_rpart[s][i];
      t2_ins(p.v0, p.i0, v0, id0, v1, id1);
      t2_ins(p.v1, p.i1, v0, id0, v1, id1);
    }
    float d0 = 2.f - 2.f * v0, d1 = 2.f - 2.f * v1;
    g_nn12[i] = id0; g_r12[i] = d0 / (d1 + 1e-8f); g_sim0[i] = v0;
  }
  {
    float v0 = -1e30f, v1 = -1e30f; int id0 = 0x7fffffff, id1 = 0x7fffffff;
    for (int p = 0; p < NCP; ++p) {
      Top2 t = g_cpart[p][i];
      t2_ins(t.v0, t.i0, v0, id0, v1, id1);
      t2_ins(t.v1, t.i1, v0, id0, v1, id1);
    }
    float d0 = 2.f - 2.f * v0, d1 = 2.f - 2.f * v1;
    g_nn21[i] = id0; g_r21[i] = d0 / (d1 + 1e-8f);
  }
}

// -------------------- kernel 4: mutual-NN + ratio mask, FP32 outputs ----------
__global__ void finalize_kernel(float* __restrict__ out) {
  int i = blockIdx.x * 256 + threadIdx.x;
  if (i >= N) return;
  int j = g_nn12[i];
  int jc = j < 0 ? 0 : (j >= N ? N - 1 : j);
  bool mask = (g_nn21[jc] == i) && (g_r12[i] <= 0.95f) && (g_r21[jc] <= 0.95f);
  out[i]         = bf16_quant(mask ? g_sim0[i] : 0.f);
  out[N + i]     = bf16_quant((float)j);
  out[2 * N + i] = mask ? 1.f : 0.f;
}

extern "C" void kernel_launch(void* const* d_in, const int* in_sizes, int n_in,
                              void* d_out, int out_size, void* d_ws, size_t ws_size,
                              hipStream_t stream) {
  const float* A = (const float*)d_in[0];  // fp32 [CH][N]
  const float* B = (const float*)d_in[1];
  (void)d_ws; (void)ws_size;

  normalize_kernel<<<dim3((N + 255) / 256), 256, 0, stream>>>(A, B);
  sim_kernel<<<dim3(NIT, NS), 256, 0, stream>>>();
  merge_kernel<<<dim3((N + 255) / 256), 256, 0, stream>>>();
  finalize_kernel<<<dim3((N + 255) / 256), 256, 0, stream>>>((float*)d_out);
}

// Round 10
// 6223.063 us; speedup vs baseline: 1.9619x; 1.9619x over previous
//
#include <hip/hip_runtime.h>
#include <stdint.h>

#define N      12288
#define CH     512
#define TI     128               // i-rows per block
#define TJ     128               // j-cols per tile
#define KC     16                // k-chunk (double-buffered)
#define NCHUNK (CH / KC)         // 32
#define NIT    (N / TI)          // 96 i-tiles
#define NJT    (N / TJ)          // 96 j-tiles
#define NS     8                 // j-slices
#define JT_PER_S (NJT / NS)      // 12 j-tiles per block

struct Top2 { float v0, v1; int i0, i1; };

// ---- module-scope device scratch (static, graph-capture safe) ----
__device__ float g_An[(size_t)CH * N];   // 25 MB normalized A
__device__ float g_Bn[(size_t)CH * N];   // 25 MB normalized B
__device__ Top2  g_rpart[NS][N];         // row top-2 partials (1.6 MB)
__device__ Top2  g_cpart[NIT][N];        // col top-2 partials (18.9 MB)
__device__ int   g_nn12[N];
__device__ float g_r12[N];
__device__ float g_sim0[N];
__device__ int   g_nn21[N];
__device__ float g_r21[N];

__device__ __forceinline__ void t2_ins(float v, int idx,
                                       float& v0, int& i0, float& v1, int& i1) {
  bool beats0 = (v > v0) || (v == v0 && idx < i0);
  bool beats1 = (v > v1) || (v == v1 && idx < i1);
  if (beats0) { v1 = v0; i1 = i0; v0 = v; i0 = idx; }
  else if (beats1) { v1 = v; i1 = idx; }
}

__device__ __forceinline__ float bf16_quant(float f) {
  unsigned int u = __float_as_uint(f);
  unsigned int r = 0x7fffu + ((u >> 16) & 1u);
  unsigned int q = ((u + r) >> 16) << 16;
  return __uint_as_float(q);
}

// async global->LDS DMA, 16 B/lane; LDS dest = wave-uniform base + lane*16
__device__ __forceinline__ void glds16(const float* g, float* l) {
  __builtin_amdgcn_global_load_lds((const __attribute__((address_space(1))) void*)g,
                                   (__attribute__((address_space(3))) void*)l, 16, 0, 0);
}

// -------------------- kernel 1: normalize descriptors --------------------
__global__ void normalize_kernel(const float* __restrict__ A,
                                 const float* __restrict__ B) {
  int i = blockIdx.x * 256 + threadIdx.x;
  if (i >= N) return;
  float sa = 0.f, sb = 0.f;
  for (int c = 0; c < CH; ++c) {
    float a = A[(size_t)c * N + i];
    float b = B[(size_t)c * N + i];
    sa += a * a;
    sb += b * b;
  }
  float na = sqrtf(sa), nb = sqrtf(sb);
  for (int c = 0; c < CH; ++c) {
    g_An[(size_t)c * N + i] = A[(size_t)c * N + i] / na;
    g_Bn[(size_t)c * N + i] = B[(size_t)c * N + i] / nb;
  }
}

// -------------------- kernel 2: sim GEMM (DMA dbuf staging) + row/col top-2 ----
// grid (96, 8): i-tile x j-slice (12 j-tiles of 128 cols). Thread tile 8x8 in
// 4x4 quadrants: rows {ty*4+u, 64+ty*4+u}, cols {tx*4+v, 64+tx*4+v} -> all LDS
// frag reads 16B-stride (2-way aliasing = free). acc = 64 VGPRs: NO SPILLS
// (R9's 8x16 tile spilled -> 35 GB scratch traffic).
__global__ __launch_bounds__(256)
void sim_kernel() {
  __shared__ float Xs[2][KC * TI];   // 16 KB
  __shared__ float Ys[2][KC * TJ];   // 16 KB
  __shared__ Top2  rowTop[TI];       // 2 KB
  __shared__ Top2  colWave[4][TJ];   // 8 KB

  const int itile = blockIdx.x;
  const int slice = blockIdx.y;
  const int i0 = itile * TI;
  const int tid  = threadIdx.x;
  const int tx = tid & 15;
  const int ty = tid >> 4;       // 0..15
  const int w  = tid >> 6;       // wave 0..3
  const int lane = tid & 63;

  if (tid < TI) {
    rowTop[tid].v0 = -1e30f; rowTop[tid].v1 = -1e30f;
    rowTop[tid].i0 = 0x7fffffff; rowTop[tid].i1 = 0x7fffffff;
  }

  // DMA lane mapping (verified R9, absmax 0): inst m covers 256 floats =
  // k-rows {2m, 2m+1}; this lane supplies k=2m+(lane>>5), col=(lane&31)*4.
  const float* gx = g_An + (size_t)(lane >> 5) * N + i0 + (lane & 31) * 4;
  const float* gy = g_Bn + (size_t)(lane >> 5) * N + (lane & 31) * 4;

#define ISSUE_CHUNK(GCH)                                                        \
  {                                                                             \
    const int jt_ = (GCH) >> 5, c_ = (GCH) & 31, buf_ = (GCH) & 1;              \
    const int kc_ = c_ * KC;                                                    \
    const int j0_ = (slice * JT_PER_S + jt_) * TJ;                              \
    _Pragma("unroll")                                                           \
    for (int t = 0; t < 2; ++t) {                                               \
      const int m = w * 2 + t;                                                  \
      glds16(gx + (size_t)(kc_ + 2 * m) * N, &Xs[buf_][m * 256]);               \
      glds16(gy + (size_t)(kc_ + 2 * m) * N + j0_, &Ys[buf_][m * 256]);         \
    }                                                                           \
  }

  ISSUE_CHUNK(0);
  int g = 0;
  float acc[8][8];

  for (int jt = 0; jt < JT_PER_S; ++jt) {
    const int j0 = (slice * JT_PER_S + jt) * TJ;
#pragma unroll
    for (int u = 0; u < 8; ++u)
#pragma unroll
      for (int v = 0; v < 8; ++v) acc[u][v] = 0.f;

    for (int c = 0; c < NCHUNK; ++c, ++g) {
      __syncthreads();                      // drains own DMA (vmcnt) + barrier
      const int gn = g + 1;
      if (gn < JT_PER_S * NCHUNK) ISSUE_CHUNK(gn);   // prefetch into other buf

      const float* xb = Xs[g & 1];
      const float* yb = Ys[g & 1];
#pragma unroll
      for (int k = 0; k < KC; ++k) {
        float a[8] __attribute__((aligned(16)));
        float b[8] __attribute__((aligned(16)));
        *reinterpret_cast<float4*>(&a[0]) = *reinterpret_cast<const float4*>(&xb[k * TI + ty * 4]);
        *reinterpret_cast<float4*>(&a[4]) = *reinterpret_cast<const float4*>(&xb[k * TI + 64 + ty * 4]);
        *reinterpret_cast<float4*>(&b[0]) = *reinterpret_cast<const float4*>(&yb[k * TJ + tx * 4]);
        *reinterpret_cast<float4*>(&b[4]) = *reinterpret_cast<const float4*>(&yb[k * TJ + 64 + tx * 4]);
#pragma unroll
        for (int u = 0; u < 8; ++u)
#pragma unroll
          for (int v = 0; v < 8; ++v)
            acc[u][v] += a[u] * b[v];
      }
    }

    // ---- epilogue: acc IS cosine sim (inputs pre-normalized) ----
    // row top-2: reduce across tx (masks 1..8)
#pragma unroll
    for (int u = 0; u < 8; ++u) {
      float v0 = -1e30f, v1 = -1e30f; int id0 = 0x7fffffff, id1 = 0x7fffffff;
#pragma unroll
      for (int v = 0; v < 8; ++v) {
        int col = (v >> 2) * 64 + tx * 4 + (v & 3);
        t2_ins(acc[u][v], j0 + col, v0, id0, v1, id1);
      }
#pragma unroll
      for (int m = 1; m < 16; m <<= 1) {
        float ov0 = __shfl_xor(v0, m), ov1 = __shfl_xor(v1, m);
        int   oi0 = __shfl_xor(id0, m), oi1 = __shfl_xor(id1, m);
        t2_ins(ov0, oi0, v0, id0, v1, id1);
        t2_ins(ov1, oi1, v0, id0, v1, id1);
      }
      if (tx == 0) {   // unique owner per row
        int row = (u >> 2) * 64 + ty * 4 + (u & 3);
        Top2 t = rowTop[row];
        t2_ins(v0, id0, t.v0, t.i0, t.v1, t.i1);
        t2_ins(v1, id1, t.v0, t.i0, t.v1, t.i1);
        rowTop[row] = t;
      }
    }

    // col top-2: reduce 8 local rows, then across ty in-wave (masks 16,32)
#pragma unroll
    for (int v = 0; v < 8; ++v) {
      float v0 = -1e30f, v1 = -1e30f; int id0 = 0x7fffffff, id1 = 0x7fffffff;
#pragma unroll
      for (int u = 0; u < 8; ++u) {
        int row = (u >> 2) * 64 + ty * 4 + (u & 3);
        t2_ins(acc[u][v], i0 + row, v0, id0, v1, id1);
      }
#pragma unroll
      for (int m = 16; m < 64; m <<= 1) {
        float ov0 = __shfl_xor(v0, m), ov1 = __shfl_xor(v1, m);
        int   oi0 = __shfl_xor(id0, m), oi1 = __shfl_xor(id1, m);
        t2_ins(ov0, oi0, v0, id0, v1, id1);
        t2_ins(ov1, oi1, v0, id0, v1, id1);
      }
      if ((lane >> 4) == 0) {
        int col = (v >> 2) * 64 + tx * 4 + (v & 3);
        Top2 t; t.v0 = v0; t.v1 = v1; t.i0 = id0; t.i1 = id1;
        colWave[w][col] = t;
      }
    }
    __syncthreads();
    if (tid < TJ) {
      Top2 t = colWave[0][tid];
#pragma unroll
      for (int ww = 1; ww < 4; ++ww) {
        Top2 o = colWave[ww][tid];
        t2_ins(o.v0, o.i0, t.v0, t.i0, t.v1, t.i1);
        t2_ins(o.v1, o.i1, t.v0, t.i0, t.v1, t.i1);
      }
      g_cpart[itile][j0 + tid] = t;
    }
  }

  __syncthreads();
  if (tid < TI) g_rpart[slice][i0 + tid] = rowTop[tid];
#undef ISSUE_CHUNK
}

// -------------------- kernel 3: merge partials --------------------
__global__ void merge_kernel() {
  int i = blockIdx.x * 256 + threadIdx.x;
  if (i >= N) return;
  {
    float v0 = -1e30f, v1 = -1e30f; int id0 = 0x7fffffff, id1 = 0x7fffffff;
#pragma unroll
    for (int s = 0; s < NS; ++s) {
      Top2 p = g_rpart[s][i];
      t2_ins(p.v0, p.i0, v0, id0, v1, id1);
      t2_ins(p.v1, p.i1, v0, id0, v1, id1);
    }
    float d0 = 2.f - 2.f * v0, d1 = 2.f - 2.f * v1;
    g_nn12[i] = id0; g_r12[i] = d0 / (d1 + 1e-8f); g_sim0[i] = v0;
  }
  {
    float v0 = -1e30f, v1 = -1e30f; int id0 = 0x7fffffff, id1 = 0x7fffffff;
    for (int p = 0; p < NIT; ++p) {
      Top2 t = g_cpart[p][i];
      t2_ins(t.v0, t.i0, v0, id0, v1, id1);
      t2_ins(t.v1, t.i1, v0, id0, v1, id1);
    }
    float d0 = 2.f - 2.f * v0, d1 = 2.f - 2.f * v1;
    g_nn21[i] = id0; g_r21[i] = d0 / (d1 + 1e-8f);
  }
}

// -------------------- kernel 4: mutual-NN + ratio mask, FP32 outputs ----------
__global__ void finalize_kernel(float* __restrict__ out) {
  int i = blockIdx.x * 256 + threadIdx.x;
  if (i >= N) return;
  int j = g_nn12[i];
  int jc = j < 0 ? 0 : (j >= N ? N - 1 : j);
  bool mask = (g_nn21[jc] == i) && (g_r12[i] <= 0.95f) && (g_r21[jc] <= 0.95f);
  out[i]         = bf16_quant(mask ? g_sim0[i] : 0.f);
  out[N + i]     = bf16_quant((float)j);
  out[2 * N + i] = mask ? 1.f : 0.f;
}

extern "C" void kernel_launch(void* const* d_in, const int* in_sizes, int n_in,
                              void* d_out, int out_size, void* d_ws, size_t ws_size,
                              hipStream_t stream) {
  const float* A = (const float*)d_in[0];  // fp32 [CH][N]
  const float* B = (const float*)d_in[1];
  (void)d_ws; (void)ws_size;

  normalize_kernel<<<dim3((N + 255) / 256), 256, 0, stream>>>(A, B);
  sim_kernel<<<dim3(NIT, NS), 256, 0, stream>>>();
  merge_kernel<<<dim3((N + 255) / 256), 256, 0, stream>>>();
  finalize_kernel<<<dim3((N + 255) / 256), 256, 0, stream>>>((float*)d_out);
}

// Round 11
// 3793.291 us; speedup vs baseline: 3.2186x; 1.6405x over previous
//
#include <hip/hip_runtime.h>
#include <stdint.h>

#define N      12288
#define CH     512
#define TI     128               // i-rows per block
#define TJ     128               // j-cols per tile
#define KC     32                // k-chunk
#define NCH    (CH / KC)         // 16 chunks per jt
#define NIT    (N / TI)          // 96 i-tiles
#define NJT    (N / TJ)          // 96 j-tiles
#define NS     8                 // j-slices
#define JT_PER_S (NJT / NS)      // 12 j-tiles per block
#define GTOT   (JT_PER_S * NCH)  // 192 chunks per block

struct Top2 { float v0, v1; int i0, i1; };

// ---- module-scope device scratch (static, graph-capture safe) ----
__device__ float g_An[(size_t)CH * N];   // 25 MB normalized A
__device__ float g_Bn[(size_t)CH * N];   // 25 MB normalized B
__device__ Top2  g_rpart[NS][N];         // row top-2 partials (1.6 MB)
__device__ Top2  g_cpart[NIT][N];        // col top-2 partials (18.9 MB)
__device__ int   g_nn12[N];
__device__ float g_r12[N];
__device__ float g_sim0[N];
__device__ int   g_nn21[N];
__device__ float g_r21[N];

__device__ __forceinline__ void t2_ins(float v, int idx,
                                       float& v0, int& i0, float& v1, int& i1) {
  bool beats0 = (v > v0) || (v == v0 && idx < i0);
  bool beats1 = (v > v1) || (v == v1 && idx < i1);
  if (beats0) { v1 = v0; i1 = i0; v0 = v; i0 = idx; }
  else if (beats1) { v1 = v; i1 = idx; }
}

__device__ __forceinline__ float bf16_quant(float f) {
  unsigned int u = __float_as_uint(f);
  unsigned int r = 0x7fffu + ((u >> 16) & 1u);
  unsigned int q = ((u + r) >> 16) << 16;
  return __uint_as_float(q);
}

// -------------------- kernel 1: normalize descriptors --------------------
__global__ void normalize_kernel(const float* __restrict__ A,
                                 const float* __restrict__ B) {
  int i = blockIdx.x * 256 + threadIdx.x;
  if (i >= N) return;
  float sa = 0.f, sb = 0.f;
  for (int c = 0; c < CH; ++c) {
    float a = A[(size_t)c * N + i];
    float b = B[(size_t)c * N + i];
    sa += a * a;
    sb += b * b;
  }
  float na = sqrtf(sa), nb = sqrtf(sb);
  for (int c = 0; c < CH; ++c) {
    g_An[(size_t)c * N + i] = A[(size_t)c * N + i] / na;
    g_Bn[(size_t)c * N + i] = B[(size_t)c * N + i] / nb;
  }
}

// -------------------- kernel 2: sim GEMM (reg-prefetch staging) + row/col top-2 ----
// grid (96, 8): i-tile x j-slice (12 j-tiles of 128 cols). Thread tile 8x8 in
// 4x4 quadrants. LDS tiles UNPADDED (128-float rows); staging writes are
// contiguous 1KB per wave (minimal bank sweeps); frag reads are broadcasts.
// Global loads for chunk g+1 issued after barrier-2, consumed at next
// barrier-1 -> latency hidden under 4096 cyc of FMA.
__global__ __launch_bounds__(256)
void sim_kernel() {
  __shared__ float Xs[KC * TI];      // 16 KB
  __shared__ float Ys[KC * TJ];      // 16 KB
  __shared__ Top2  rowTop[TI];       // 2 KB
  __shared__ Top2  colWave[4][TJ];   // 8 KB

  const int itile = blockIdx.x;
  const int slice = blockIdx.y;
  const int i0 = itile * TI;
  const int tid  = threadIdx.x;
  const int tx = tid & 15;
  const int ty = tid >> 4;       // 0..15
  const int w  = tid >> 6;       // wave 0..3
  const int lane = tid & 63;

  if (tid < TI) {
    rowTop[tid].v0 = -1e30f; rowTop[tid].v1 = -1e30f;
    rowTop[tid].i0 = 0x7fffffff; rowTop[tid].i1 = 0x7fffffff;
  }

  // staging map: inst t (0..3) <-> LDS word 1024t + 4*tid
  //   = row k = 8t + (tid>>5), col c = (tid&31)*4  (global: coalesced 512B/32 lanes)
  const int lk = tid >> 5;          // 0..7
  const int lc = (tid & 31) * 4;    // 0..124

  float4 px[4], py[4];

#define LOAD_CHUNK(G)                                                          \
  {                                                                            \
    const int jt_ = (G) >> 4, cc_ = (G) & 15;                                  \
    const int kc_ = cc_ * KC;                                                  \
    const int j0_ = (slice * JT_PER_S + jt_) * TJ;                             \
    _Pragma("unroll")                                                          \
    for (int t = 0; t < 4; ++t) {                                              \
      const size_t krow = (size_t)(kc_ + 8 * t + lk) * N;                      \
      px[t] = *reinterpret_cast<const float4*>(&g_An[krow + i0 + lc]);         \
      py[t] = *reinterpret_cast<const float4*>(&g_Bn[krow + j0_ + lc]);        \
    }                                                                          \
  }

  LOAD_CHUNK(0);
  int g = 0;
  float acc[8][8];

  for (int jt = 0; jt < JT_PER_S; ++jt) {
    const int j0 = (slice * JT_PER_S + jt) * TJ;
#pragma unroll
    for (int u = 0; u < 8; ++u)
#pragma unroll
      for (int v = 0; v < 8; ++v) acc[u][v] = 0.f;

    for (int cc = 0; cc < NCH; ++cc, ++g) {
      __syncthreads();                 // prev chunk's LDS readers done
#pragma unroll
      for (int t = 0; t < 4; ++t) {    // contiguous wave writes: no conflicts
        *reinterpret_cast<float4*>(&Xs[t * 1024 + tid * 4]) = px[t];
        *reinterpret_cast<float4*>(&Ys[t * 1024 + tid * 4]) = py[t];
      }
      __syncthreads();
      if (g + 1 < GTOT) LOAD_CHUNK(g + 1);   // prefetch: hidden under compute

#pragma unroll 8
      for (int k = 0; k < KC; ++k) {
        float a[8] __attribute__((aligned(16)));
        float b[8] __attribute__((aligned(16)));
        *reinterpret_cast<float4*>(&a[0]) = *reinterpret_cast<const float4*>(&Xs[k * TI + ty * 4]);
        *reinterpret_cast<float4*>(&a[4]) = *reinterpret_cast<const float4*>(&Xs[k * TI + 64 + ty * 4]);
        *reinterpret_cast<float4*>(&b[0]) = *reinterpret_cast<const float4*>(&Ys[k * TJ + tx * 4]);
        *reinterpret_cast<float4*>(&b[4]) = *reinterpret_cast<const float4*>(&Ys[k * TJ + 64 + tx * 4]);
#pragma unroll
        for (int u = 0; u < 8; ++u)
#pragma unroll
          for (int v = 0; v < 8; ++v)
            acc[u][v] += a[u] * b[v];
      }
    }

    // ---- epilogue (verified absmax 0): acc IS cosine sim ----
    // row top-2: reduce across tx (masks 1..8)
#pragma unroll
    for (int u = 0; u < 8; ++u) {
      float v0 = -1e30f, v1 = -1e30f; int id0 = 0x7fffffff, id1 = 0x7fffffff;
#pragma unroll
      for (int v = 0; v < 8; ++v) {
        int col = (v >> 2) * 64 + tx * 4 + (v & 3);
        t2_ins(acc[u][v], j0 + col, v0, id0, v1, id1);
      }
#pragma unroll
      for (int m = 1; m < 16; m <<= 1) {
        float ov0 = __shfl_xor(v0, m), ov1 = __shfl_xor(v1, m);
        int   oi0 = __shfl_xor(id0, m), oi1 = __shfl_xor(id1, m);
        t2_ins(ov0, oi0, v0, id0, v1, id1);
        t2_ins(ov1, oi1, v0, id0, v1, id1);
      }
      if (tx == 0) {   // unique owner per row
        int row = (u >> 2) * 64 + ty * 4 + (u & 3);
        Top2 t = rowTop[row];
        t2_ins(v0, id0, t.v0, t.i0, t.v1, t.i1);
        t2_ins(v1, id1, t.v0, t.i0, t.v1, t.i1);
        rowTop[row] = t;
      }
    }

    // col top-2: reduce 8 local rows, then across ty in-wave (masks 16,32)
#pragma unroll
    for (int v = 0; v < 8; ++v) {
      float v0 = -1e30f, v1 = -1e30f; int id0 = 0x7fffffff, id1 = 0x7fffffff;
#pragma unroll
      for (int u = 0; u < 8; ++u) {
        int row = (u >> 2) * 64 + ty * 4 + (u & 3);
        t2_ins(acc[u][v], i0 + row, v0, id0, v1, id1);
      }
#pragma unroll
      for (int m = 16; m < 64; m <<= 1) {
        float ov0 = __shfl_xor(v0, m), ov1 = __shfl_xor(v1, m);
        int   oi0 = __shfl_xor(id0, m), oi1 = __shfl_xor(id1, m);
        t2_ins(ov0, oi0, v0, id0, v1, id1);
        t2_ins(ov1, oi1, v0, id0, v1, id1);
      }
      if ((lane >> 4) == 0) {
        int col = (v >> 2) * 64 + tx * 4 + (v & 3);
        Top2 t; t.v0 = v0; t.v1 = v1; t.i0 = id0; t.i1 = id1;
        colWave[w][col] = t;
      }
    }
    __syncthreads();
    if (tid < TJ) {
      Top2 t = colWave[0][tid];
#pragma unroll
      for (int ww = 1; ww < 4; ++ww) {
        Top2 o = colWave[ww][tid];
        t2_ins(o.v0, o.i0, t.v0, t.i0, t.v1, t.i1);
        t2_ins(o.v1, o.i1, t.v0, t.i0, t.v1, t.i1);
      }
      g_cpart[itile][j0 + tid] = t;
    }
  }

  __syncthreads();
  if (tid < TI) g_rpart[slice][i0 + tid] = rowTop[tid];
#undef LOAD_CHUNK
}

// -------------------- kernel 3: merge partials --------------------
__global__ void merge_kernel() {
  int i = blockIdx.x * 256 + threadIdx.x;
  if (i >= N) return;
  {
    float v0 = -1e30f, v1 = -1e30f; int id0 = 0x7fffffff, id1 = 0x7fffffff;
#pragma unroll
    for (int s = 0; s < NS; ++s) {
      Top2 p = g_rpart[s][i];
      t2_ins(p.v0, p.i0, v0, id0, v1, id1);
      t2_ins(p.v1, p.i1, v0, id0, v1, id1);
    }
    float d0 = 2.f - 2.f * v0, d1 = 2.f - 2.f * v1;
    g_nn12[i] = id0; g_r12[i] = d0 / (d1 + 1e-8f); g_sim0[i] = v0;
  }
  {
    float v0 = -1e30f, v1 = -1e30f; int id0 = 0x7fffffff, id1 = 0x7fffffff;
    for (int p = 0; p < NIT; ++p) {
      Top2 t = g_cpart[p][i];
      t2_ins(t.v0, t.i0, v0, id0, v1, id1);
      t2_ins(t.v1, t.i1, v0, id0, v1, id1);
    }
    float d0 = 2.f - 2.f * v0, d1 = 2.f - 2.f * v1;
    g_nn21[i] = id0; g_r21[i] = d0 / (d1 + 1e-8f);
  }
}

// -------------------- kernel 4: mutual-NN + ratio mask, FP32 outputs ----------
__global__ void finalize_kernel(float* __restrict__ out) {
  int i = blockIdx.x * 256 + threadIdx.x;
  if (i >= N) return;
  int j = g_nn12[i];
  int jc = j < 0 ? 0 : (j >= N ? N - 1 : j);
  bool mask = (g_nn21[jc] == i) && (g_r12[i] <= 0.95f) && (g_r21[jc] <= 0.95f);
  out[i]         = bf16_quant(mask ? g_sim0[i] : 0.f);
  out[N + i]     = bf16_quant((float)j);
  out[2 * N + i] = mask ? 1.f : 0.f;
}

extern "C" void kernel_launch(void* const* d_in, const int* in_sizes, int n_in,
                              void* d_out, int out_size, void* d_ws, size_t ws_size,
                              hipStream_t stream) {
  const float* A = (const float*)d_in[0];  // fp32 [CH][N]
  const float* B = (const float*)d_in[1];
  (void)d_ws; (void)ws_size;

  normalize_kernel<<<dim3((N + 255) / 256), 256, 0, stream>>>(A, B);
  sim_kernel<<<dim3(NIT, NS), 256, 0, stream>>>();
  merge_kernel<<<dim3((N + 255) / 256), 256, 0, stream>>>();
  finalize_kernel<<<dim3((N + 255) / 256), 256, 0, stream>>>((float*)d_out);
}